// Round 16
// baseline (188.137 us; speedup 1.0000x reference)
//
#include <hip/hip_runtime.h>

// B=2, N=8192, K=10, I=3, LEN_IN=66. All buffers f32.
// LOCKED correctness recipe (R8-R15, passed, absmax 0.0625):
//   sq  = fmaf(z,z, fmaf(y,y, rn(x*x)))          (asc FMA)
//   dot = fmaf(z,z', fmaf(y,y', rn(x*x')))       (asc FMA)
//   d2  = fmaf(-2,dot, rn(sq_q + sq_c))          (== single-rounded sub form)
//   selection: strict <, stable lowest-index-first (lexicographic (d2,idx))
// R16: shared gate, attempt 3. R14 (+ds_read/iter) and R15 (+4x inlined flush
// copies) both regressed by ADDING hot-loop structure. This round is R13's
// loop byte-for-byte; gate lives in a register, compare swaps < thr -> <= gate
// (same instr count). Refresh ONLY in the rare flush path + a uniform scalar
// branch every 64 candidates (8 lane-indexed ds_reads per scan).
#define NPTS   8192
#define KNN    11
#define QPB    64          // queries per block (one per lane)
#define NTHR   1024
#define NSLICE 16          // candidate slices (one per wave)
#define SLEN   (NPTS / NSLICE)   // 512
#define DEPTH  10          // per-lane push-buffer entries
#define TRIG   7           // flush when any lane cnt >= TRIG (4 pushes headroom)

__global__ __launch_bounds__(NTHR, 4) void knn_mlp(
    const float* __restrict__ pos,
    const float* __restrict__ vel,
    const float* __restrict__ initc,
    const float* __restrict__ W1,
    const float* __restrict__ b1,
    const float* __restrict__ W2,
    const float* __restrict__ b2,
    const float* __restrict__ W3,
    const float* __restrict__ b3,
    float* __restrict__ out) {

    // Phased LDS (112KB):
    //   phase-scan : [0,32K) ssq | [32K,112K) push region [k][tid] u64
    //   phase-fold : [32K, ...) fold scratch (4.3KB)
    //   phase-merge: [0,45K) pd f32 | [45K,90K) pi i32   (ssq/region dead)
    __shared__ __align__(16) char smem[32 * 1024 + NTHR * DEPTH * 8];
    __shared__ float sW[405];           // Weff[396] + bias[6] + init[3]
    __shared__ unsigned sthrB[QPB];     // shared per-query threshold (f32 bits)

    float* ssq = (float*)smem;
    unsigned long long* region = (unsigned long long*)(smem + 32 * 1024);

    const int tid  = threadIdx.x;
    const int lane = tid & 63;
    const int wave = tid >> 6;
    const int b    = blockIdx.x >> 7;           // 128 blocks per batch
    const int n0   = (blockIdx.x & 127) * QPB;
    const int q    = n0 + lane;

    const float* posb = pos + b * NPTS * 3;
    const float* velb = vel + b * NPTS * 3;

    // ---- phase 1a: per-point sq into LDS (LOCKED recipe)
    for (int a = tid; a < NPTS; a += NTHR) {
        float x = posb[a * 3 + 0];
        float y = posb[a * 3 + 1];
        float z = posb[a * 3 + 2];
        ssq[a] = __fmaf_rn(z, z, __fmaf_rn(y, y, __fmul_rn(x, x)));
    }
    // ---- phase 1b: fold stage 1 (scratch in region): W12 = W1@W2, b12 = b1@W2+b2
    float* sW12 = (float*)region;
    for (int e = tid; e < 66 * 16; e += NTHR) {
        int r = e >> 4, c = e & 15;
        float s = 0.f;
        for (int j = 0; j < 32; ++j) s += W1[r * 32 + j] * W2[j * 16 + c];
        sW12[e] = s;
    }
    if (tid < 16) {
        float s = b2[tid];
        for (int j = 0; j < 32; ++j) s += b1[j] * W2[j * 16 + tid];
        sW12[66 * 16 + tid] = s;
    }
    if (tid < 3) sW[402 + tid] = initc[b * 3 + tid];
    if (tid < QPB) sthrB[tid] = 0x7F7FFFFFu;    // bits of FLT_MAX
    __syncthreads();
    // ---- fold stage 2: Weff = W12@W3, bias = b12@W3 + b3
    for (int e = tid; e < 66 * 6; e += NTHR) {
        int r = e / 6, c = e - r * 6;
        float s = 0.f;
        for (int j = 0; j < 16; ++j) s += sW12[r * 16 + j] * W3[j * 6 + c];
        sW[e] = s;
    }
    if (tid < 6) {
        float s = b3[tid];
        for (int j = 0; j < 16; ++j) s += sW12[66 * 16 + j] * W3[j * 6 + tid];
        sW[396 + tid] = s;
    }
    __syncthreads();   // fold scratch done -> region becomes push buffers

    const float qx = posb[q * 3 + 0];
    const float qy = posb[q * 3 + 1];
    const float qz = posb[q * 3 + 2];
    const float sqq = ssq[q];           // identical bits to locked recipe

    // Top-11 in named scalars (register-resident; 52 VGPR verified legit R13-R15).
    float d0 = 3.0e38f, d1 = 3.0e38f, d2v = 3.0e38f, d3 = 3.0e38f, d4 = 3.0e38f,
          d5 = 3.0e38f, d6 = 3.0e38f, d7 = 3.0e38f, d8 = 3.0e38f, d9 = 3.0e38f,
          d10 = 3.0e38f;
    int   i0 = 0x7FFFFFFF, i1 = 0x7FFFFFFF, i2v = 0x7FFFFFFF, i3 = 0x7FFFFFFF,
          i4 = 0x7FFFFFFF, i5 = 0x7FFFFFFF, i6 = 0x7FFFFFFF, i7 = 0x7FFFFFFF,
          i8 = 0x7FFFFFFF, i9 = 0x7FFFFFFF, i10 = 0x7FFFFFFF;

    float thr  = 3.0e38f;      // own d10 copy (stale ok)
    float gate = 3.0e38f;      // min(own thr, shared) — register only
    int cnt = 0;

    auto insert = [&](float nd, int nj) {
        if (nd < d10) {
            bool c, cp;
            cp = nd < d9;  d10 = cp ? d9  : nd;             i10 = cp ? i9  : nj;             c = cp;
            cp = nd < d8;  d9  = cp ? d8  : (c ? nd : d9);  i9  = cp ? i8  : (c ? nj : i9);  c = cp;
            cp = nd < d7;  d8  = cp ? d7  : (c ? nd : d8);  i8  = cp ? i7  : (c ? nj : i8);  c = cp;
            cp = nd < d6;  d7  = cp ? d6  : (c ? nd : d7);  i7  = cp ? i6  : (c ? nj : i7);  c = cp;
            cp = nd < d5;  d6  = cp ? d5  : (c ? nd : d6);  i6  = cp ? i5  : (c ? nj : i6);  c = cp;
            cp = nd < d4;  d5  = cp ? d4  : (c ? nd : d5);  i5  = cp ? i4  : (c ? nj : i5);  c = cp;
            cp = nd < d3;  d4  = cp ? d3  : (c ? nd : d4);  i4  = cp ? i3  : (c ? nj : i4);  c = cp;
            cp = nd < d2v; d3  = cp ? d2v : (c ? nd : d3);  i3  = cp ? i2v : (c ? nj : i3);  c = cp;
            cp = nd < d1;  d2v = cp ? d1  : (c ? nd : d2v); i2v = cp ? i1  : (c ? nj : i2v); c = cp;
            cp = nd < d0;  d1  = cp ? d0  : (c ? nd : d1);  i1  = cp ? i0  : (c ? nj : i1);  c = cp;
            if (c) { d0 = nd; i0 = nj; }
        }
    };

    auto flush = [&]() {
#pragma unroll 1
        for (int k = 0; __any(k < cnt); ++k) {
            if (k < cnt) {
                unsigned long long e = region[k * NTHR + tid];  // [k][tid]: 2-way only
                float nd = __uint_as_float((unsigned)(e >> 32));
                int   nj = (int)(unsigned)(e & 0xFFFFFFFFull);
                insert(nd, nj);
            }
        }
        cnt = 0;
        thr = d10;
        atomicMin(&sthrB[lane], __float_as_uint(d10));            // publish (monotone)
        gate = fminf(thr, __uint_as_float(sthrB[lane]));          // read back block min
    };

    auto proc = [&](float cx, float cy, float cz, float sqc, int j) {
        float dot = __fmaf_rn(qz, cz, __fmaf_rn(qy, cy, __fmul_rn(qx, cx)));
        float dd  = __fmaf_rn(-2.0f, dot, __fadd_rn(sqq, sqc)); // == rn(s-2dot)
        if (dd <= gate) {   // <= : boundary-tie elements always captured
            region[cnt * NTHR + tid] =
                (((unsigned long long)__float_as_uint(dd)) << 32) | (unsigned)j;
            ++cnt;
        }
    };

    // ---- scan: wave streams its 512-candidate slice from global (L2-hot).
    // Flat loop, single flush site (R13 shape — the only one that's fast).
    const int base = wave * SLEN;
    const float4* gp = (const float4*)(posb + base * 3);  // 3 float4 per 4 cands
    const float4* sp = (const float4*)(ssq + base);
#pragma unroll 1
    for (int m = 0; m < SLEN; m += 4) {
        if ((m & 63) == 0)                                // uniform scalar branch
            gate = fminf(thr, __uint_as_float(sthrB[lane]));
        int f = (m >> 2) * 3;
        float4 A = gp[f], Bv = gp[f + 1], C = gp[f + 2];
        float4 S = sp[m >> 2];
        int j = base + m;
        proc(A.x,  A.y,  A.z,  S.x, j + 0);
        proc(A.w,  Bv.x, Bv.y, S.y, j + 1);
        proc(Bv.z, Bv.w, C.x,  S.z, j + 2);
        proc(C.y,  C.z,  C.w,  S.w, j + 3);
        if (__any(cnt >= TRIG)) flush();                  // rare wave-uniform path
    }
    flush();

    __syncthreads();   // scans done -> smem becomes merge lists
    float* pd = (float*)smem;                       // [NTHR][11] f32
    int*   pi = (int*)(smem + NTHR * KNN * 4);      // [NTHR][11] i32
    {
        float* pw = pd + tid * KNN;
        int*   iw = pi + tid * KNN;
        pw[0] = d0;  pw[1] = d1;  pw[2] = d2v; pw[3] = d3;  pw[4] = d4;
        pw[5] = d5;  pw[6] = d6;  pw[7] = d7;  pw[8] = d8;  pw[9] = d9;
        pw[10] = d10;
        iw[0] = i0;  iw[1] = i1;  iw[2] = i2v; iw[3] = i3;  iw[4] = i4;
        iw[5] = i5;  iw[6] = i6;  iw[7] = i7;  iw[8] = i8;  iw[9] = i9;
        iw[10] = i10;
    }
    __syncthreads();

    if (tid < QPB) {
        // 16-way merge, lexicographic (d2, idx) == global stable top-11.
        int p[NSLICE]; float hd[NSLICE]; int hi[NSLICE];
#pragma unroll
        for (int s = 0; s < NSLICE; ++s) {
            p[s]  = 0;
            hd[s] = pd[(s * 64 + tid) * KNN];
            hi[s] = pi[(s * 64 + tid) * KNN];
        }
        float acc[6];
#pragma unroll
        for (int c = 0; c < 6; ++c) acc[c] = sW[396 + c];

        for (int r = 0; r < KNN; ++r) {
            float bd = 3.9e38f; int bi = 0x7FFFFFFF; int bs = 0;
#pragma unroll
            for (int s = 0; s < NSLICE; ++s) {
                bool better = (hd[s] < bd) || (hd[s] == bd && hi[s] < bi);
                bs = better ? s : bs;
                bi = better ? hi[s] : bi;
                bd = better ? hd[s] : bd;
            }
            {   // advance winning slice head
                int pp = ++p[bs];
                if (pp < KNN) {
                    hd[bs] = pd[(bs * 64 + tid) * KNN + pp];
                    hi[bs] = pi[(bs * 64 + tid) * KNN + pp];
                } else { hd[bs] = 3.9e38f; hi[bs] = 0x7FFFFFFF; }
            }

            int bg = ((unsigned)bi < (unsigned)NPTS) ? bi : 0;   // defensive

            // velocity features: slots [r*3 .. r*3+2]
            const float* vp = velb + bg * 3;
            float vx = vp[0], vy = vp[1], vz = vp[2];
            const float* w = &sW[r * 18];
#pragma unroll
            for (int c = 0; c < 6; ++c) {
                acc[c] += vx * w[c];
                acc[c] += vy * w[6 + c];
                acc[c] += vz * w[12 + c];
            }
            // offset features (positions from global, L2-hot): rank 0 = self
            if (r >= 1) {
                float ox = posb[bg * 3 + 0] - qx;
                float oy = posb[bg * 3 + 1] - qy;
                float oz = posb[bg * 3 + 2] - qz;
                const float* w2 = &sW[(33 + (r - 1) * 3) * 6];
#pragma unroll
                for (int c = 0; c < 6; ++c) {
                    acc[c] += ox * w2[c];
                    acc[c] += oy * w2[6 + c];
                    acc[c] += oz * w2[12 + c];
                }
            }
        }
        // init_config features: slots [63..65]
#pragma unroll
        for (int k3 = 0; k3 < 3; ++k3) {
            const float* w3 = &sW[(63 + k3) * 6];
            float iv = sW[402 + k3];
#pragma unroll
            for (int c = 0; c < 6; ++c) acc[c] += iv * w3[c];
        }
        acc[0] += qx; acc[1] += qy; acc[2] += qz;

        float* op = out + (b * NPTS + q) * 6;
#pragma unroll
        for (int c = 0; c < 6; ++c) op[c] = acc[c];
    }
}

extern "C" void kernel_launch(void* const* d_in, const int* in_sizes, int n_in,
                              void* d_out, int out_size, void* d_ws, size_t ws_size,
                              hipStream_t stream) {
    (void)in_sizes; (void)n_in; (void)out_size; (void)d_ws; (void)ws_size;
    const float* pos   = (const float*)d_in[0];
    const float* vel   = (const float*)d_in[1];
    const float* initc = (const float*)d_in[2];
    const float* W1    = (const float*)d_in[3];
    const float* b1    = (const float*)d_in[4];
    const float* W2    = (const float*)d_in[5];
    const float* b2    = (const float*)d_in[6];
    const float* W3    = (const float*)d_in[7];
    const float* b3    = (const float*)d_in[8];
    float* out = (float*)d_out;

    knn_mlp<<<256, NTHR, 0, stream>>>(pos, vel, initc, W1, b1, W2, b2, W3, b3, out);
}

// Round 17
// 181.444 us; speedup vs baseline: 1.0369x; 1.0369x over previous
//
#include <hip/hip_runtime.h>

// B=2, N=8192, K=10, I=3, LEN_IN=66. All buffers f32.
// LOCKED correctness recipe (R8-R16, passed, absmax 0.0625):
//   sq  = fmaf(z,z, fmaf(y,y, rn(x*x)))          (asc FMA)
//   dot = fmaf(z,z', fmaf(y,y', rn(x*x')))       (asc FMA)
//   d2  = fmaf(-2,dot, rn(sq_q + sq_c))          (== single-rounded sub form)
//   selection: strict <, stable lowest-index-first (lexicographic (d2,idx))
// R17: revert to R13 (best: 116.9us) + ONE change: software prefetch of the
// next iteration's 4 candidates (R11's idea, un-confounded: VGPR 52->~72 fits
// the 128 cap at 4 waves/SIMD, no spills expected). Shared-gate idea is DEAD:
// R14/R15/R16 all regressed (+issue > -flush). Flat loop, single flush site.
#define NPTS   8192
#define KNN    11
#define QPB    64          // queries per block (one per lane)
#define NTHR   1024
#define NSLICE 16          // candidate slices (one per wave)
#define SLEN   (NPTS / NSLICE)   // 512
#define DEPTH  10          // per-lane push-buffer entries
#define TRIG   7           // flush when any lane cnt >= TRIG (4 pushes headroom)

__global__ __launch_bounds__(NTHR, 4) void knn_mlp(
    const float* __restrict__ pos,
    const float* __restrict__ vel,
    const float* __restrict__ initc,
    const float* __restrict__ W1,
    const float* __restrict__ b1,
    const float* __restrict__ W2,
    const float* __restrict__ b2,
    const float* __restrict__ W3,
    const float* __restrict__ b3,
    float* __restrict__ out) {

    // Phased LDS (112KB):
    //   phase-scan : [0,32K) ssq | [32K,112K) push region [k][tid] u64
    //   phase-fold : [32K, ...) fold scratch (4.3KB)
    //   phase-merge: [0,45K) pd f32 | [45K,90K) pi i32   (ssq/region dead)
    __shared__ __align__(16) char smem[32 * 1024 + NTHR * DEPTH * 8];
    __shared__ float sW[405];           // Weff[396] + bias[6] + init[3]

    float* ssq = (float*)smem;
    unsigned long long* region = (unsigned long long*)(smem + 32 * 1024);

    const int tid  = threadIdx.x;
    const int lane = tid & 63;
    const int wave = tid >> 6;
    const int b    = blockIdx.x >> 7;           // 128 blocks per batch
    const int n0   = (blockIdx.x & 127) * QPB;
    const int q    = n0 + lane;

    const float* posb = pos + b * NPTS * 3;
    const float* velb = vel + b * NPTS * 3;

    // ---- phase 1a: per-point sq into LDS (LOCKED recipe)
    for (int a = tid; a < NPTS; a += NTHR) {
        float x = posb[a * 3 + 0];
        float y = posb[a * 3 + 1];
        float z = posb[a * 3 + 2];
        ssq[a] = __fmaf_rn(z, z, __fmaf_rn(y, y, __fmul_rn(x, x)));
    }
    // ---- phase 1b: fold stage 1 (scratch in region): W12 = W1@W2, b12 = b1@W2+b2
    float* sW12 = (float*)region;
    for (int e = tid; e < 66 * 16; e += NTHR) {
        int r = e >> 4, c = e & 15;
        float s = 0.f;
        for (int j = 0; j < 32; ++j) s += W1[r * 32 + j] * W2[j * 16 + c];
        sW12[e] = s;
    }
    if (tid < 16) {
        float s = b2[tid];
        for (int j = 0; j < 32; ++j) s += b1[j] * W2[j * 16 + tid];
        sW12[66 * 16 + tid] = s;
    }
    if (tid < 3) sW[402 + tid] = initc[b * 3 + tid];
    __syncthreads();
    // ---- fold stage 2: Weff = W12@W3, bias = b12@W3 + b3
    for (int e = tid; e < 66 * 6; e += NTHR) {
        int r = e / 6, c = e - r * 6;
        float s = 0.f;
        for (int j = 0; j < 16; ++j) s += sW12[r * 16 + j] * W3[j * 6 + c];
        sW[e] = s;
    }
    if (tid < 6) {
        float s = b3[tid];
        for (int j = 0; j < 16; ++j) s += sW12[66 * 16 + j] * W3[j * 6 + tid];
        sW[396 + tid] = s;
    }
    __syncthreads();   // fold scratch done -> region becomes push buffers

    const float qx = posb[q * 3 + 0];
    const float qy = posb[q * 3 + 1];
    const float qz = posb[q * 3 + 2];
    const float sqq = ssq[q];           // identical bits to locked recipe

    // Top-11 in named scalars (register-resident; 52 VGPR verified legit).
    float d0 = 3.0e38f, d1 = 3.0e38f, d2v = 3.0e38f, d3 = 3.0e38f, d4 = 3.0e38f,
          d5 = 3.0e38f, d6 = 3.0e38f, d7 = 3.0e38f, d8 = 3.0e38f, d9 = 3.0e38f,
          d10 = 3.0e38f;
    int   i0 = 0x7FFFFFFF, i1 = 0x7FFFFFFF, i2v = 0x7FFFFFFF, i3 = 0x7FFFFFFF,
          i4 = 0x7FFFFFFF, i5 = 0x7FFFFFFF, i6 = 0x7FFFFFFF, i7 = 0x7FFFFFFF,
          i8 = 0x7FFFFFFF, i9 = 0x7FFFFFFF, i10 = 0x7FFFFFFF;

    float thr = 3.0e38f;       // own d10 copy (stale ok: only over-buffers)
    int cnt = 0;

    auto insert = [&](float nd, int nj) {
        if (nd < d10) {
            bool c, cp;
            cp = nd < d9;  d10 = cp ? d9  : nd;             i10 = cp ? i9  : nj;             c = cp;
            cp = nd < d8;  d9  = cp ? d8  : (c ? nd : d9);  i9  = cp ? i8  : (c ? nj : i9);  c = cp;
            cp = nd < d7;  d8  = cp ? d7  : (c ? nd : d8);  i8  = cp ? i7  : (c ? nj : i8);  c = cp;
            cp = nd < d6;  d7  = cp ? d6  : (c ? nd : d7);  i7  = cp ? i6  : (c ? nj : i7);  c = cp;
            cp = nd < d5;  d6  = cp ? d5  : (c ? nd : d6);  i6  = cp ? i5  : (c ? nj : i6);  c = cp;
            cp = nd < d4;  d5  = cp ? d4  : (c ? nd : d5);  i5  = cp ? i4  : (c ? nj : i5);  c = cp;
            cp = nd < d3;  d4  = cp ? d3  : (c ? nd : d4);  i4  = cp ? i3  : (c ? nj : i4);  c = cp;
            cp = nd < d2v; d3  = cp ? d2v : (c ? nd : d3);  i3  = cp ? i2v : (c ? nj : i3);  c = cp;
            cp = nd < d1;  d2v = cp ? d1  : (c ? nd : d2v); i2v = cp ? i1  : (c ? nj : i2v); c = cp;
            cp = nd < d0;  d1  = cp ? d0  : (c ? nd : d1);  i1  = cp ? i0  : (c ? nj : i1);  c = cp;
            if (c) { d0 = nd; i0 = nj; }
        }
    };

    auto flush = [&]() {
#pragma unroll 1
        for (int k = 0; __any(k < cnt); ++k) {
            if (k < cnt) {
                unsigned long long e = region[k * NTHR + tid];  // [k][tid]: 2-way only
                float nd = __uint_as_float((unsigned)(e >> 32));
                int   nj = (int)(unsigned)(e & 0xFFFFFFFFull);
                insert(nd, nj);
            }
        }
        cnt = 0;
        thr = d10;
    };

    auto proc = [&](float cx, float cy, float cz, float sqc, int j) {
        float dot = __fmaf_rn(qz, cz, __fmaf_rn(qy, cy, __fmul_rn(qx, cx)));
        float dd  = __fmaf_rn(-2.0f, dot, __fadd_rn(sqq, sqc)); // == rn(s-2dot)
        if (dd < thr) {
            region[cnt * NTHR + tid] =
                (((unsigned long long)__float_as_uint(dd)) << 32) | (unsigned)j;
            ++cnt;
        }
    };

    // ---- scan: flat loop, single flush site (R13 shape), + software prefetch
    // of the next iteration's 4 candidates (covers ~200cyc L2 latency in-wave).
    const int base = wave * SLEN;
    const float4* gp = (const float4*)(posb + base * 3);  // 3 float4 per 4 cands
    const float4* sp = (const float4*)(ssq + base);
    float4 A = gp[0], Bv = gp[1], C = gp[2];
    float4 S = sp[0];
#pragma unroll 1
    for (int m = 0; m < SLEN; m += 4) {
        int mn = (m + 4 < SLEN) ? (m + 4) : 0;            // wrap: value unused
        int fn = (mn >> 2) * 3;
        float4 nA = gp[fn], nB = gp[fn + 1], nC = gp[fn + 2];
        float4 nS = sp[mn >> 2];
        int j = base + m;
        proc(A.x,  A.y,  A.z,  S.x, j + 0);
        proc(A.w,  Bv.x, Bv.y, S.y, j + 1);
        proc(Bv.z, Bv.w, C.x,  S.z, j + 2);
        proc(C.y,  C.z,  C.w,  S.w, j + 3);
        if (__any(cnt >= TRIG)) flush();                  // rare wave-uniform path
        A = nA; Bv = nB; C = nC; S = nS;
    }
    flush();

    __syncthreads();   // scans done -> smem becomes merge lists
    float* pd = (float*)smem;                       // [NTHR][11] f32
    int*   pi = (int*)(smem + NTHR * KNN * 4);      // [NTHR][11] i32
    {
        float* pw = pd + tid * KNN;
        int*   iw = pi + tid * KNN;
        pw[0] = d0;  pw[1] = d1;  pw[2] = d2v; pw[3] = d3;  pw[4] = d4;
        pw[5] = d5;  pw[6] = d6;  pw[7] = d7;  pw[8] = d8;  pw[9] = d9;
        pw[10] = d10;
        iw[0] = i0;  iw[1] = i1;  iw[2] = i2v; iw[3] = i3;  iw[4] = i4;
        iw[5] = i5;  iw[6] = i6;  iw[7] = i7;  iw[8] = i8;  iw[9] = i9;
        iw[10] = i10;
    }
    __syncthreads();

    if (tid < QPB) {
        // 16-way merge, lexicographic (d2, idx) == global stable top-11.
        int p[NSLICE]; float hd[NSLICE]; int hi[NSLICE];
#pragma unroll
        for (int s = 0; s < NSLICE; ++s) {
            p[s]  = 0;
            hd[s] = pd[(s * 64 + tid) * KNN];
            hi[s] = pi[(s * 64 + tid) * KNN];
        }
        float acc[6];
#pragma unroll
        for (int c = 0; c < 6; ++c) acc[c] = sW[396 + c];

        for (int r = 0; r < KNN; ++r) {
            float bd = 3.9e38f; int bi = 0x7FFFFFFF; int bs = 0;
#pragma unroll
            for (int s = 0; s < NSLICE; ++s) {
                bool better = (hd[s] < bd) || (hd[s] == bd && hi[s] < bi);
                bs = better ? s : bs;
                bi = better ? hi[s] : bi;
                bd = better ? hd[s] : bd;
            }
            {   // advance winning slice head
                int pp = ++p[bs];
                if (pp < KNN) {
                    hd[bs] = pd[(bs * 64 + tid) * KNN + pp];
                    hi[bs] = pi[(bs * 64 + tid) * KNN + pp];
                } else { hd[bs] = 3.9e38f; hi[bs] = 0x7FFFFFFF; }
            }

            int bg = ((unsigned)bi < (unsigned)NPTS) ? bi : 0;   // defensive

            // velocity features: slots [r*3 .. r*3+2]
            const float* vp = velb + bg * 3;
            float vx = vp[0], vy = vp[1], vz = vp[2];
            const float* w = &sW[r * 18];
#pragma unroll
            for (int c = 0; c < 6; ++c) {
                acc[c] += vx * w[c];
                acc[c] += vy * w[6 + c];
                acc[c] += vz * w[12 + c];
            }
            // offset features (positions from global, L2-hot): rank 0 = self
            if (r >= 1) {
                float ox = posb[bg * 3 + 0] - qx;
                float oy = posb[bg * 3 + 1] - qy;
                float oz = posb[bg * 3 + 2] - qz;
                const float* w2 = &sW[(33 + (r - 1) * 3) * 6];
#pragma unroll
                for (int c = 0; c < 6; ++c) {
                    acc[c] += ox * w2[c];
                    acc[c] += oy * w2[6 + c];
                    acc[c] += oz * w2[12 + c];
                }
            }
        }
        // init_config features: slots [63..65]
#pragma unroll
        for (int k3 = 0; k3 < 3; ++k3) {
            const float* w3 = &sW[(63 + k3) * 6];
            float iv = sW[402 + k3];
#pragma unroll
            for (int c = 0; c < 6; ++c) acc[c] += iv * w3[c];
        }
        acc[0] += qx; acc[1] += qy; acc[2] += qz;

        float* op = out + (b * NPTS + q) * 6;
#pragma unroll
        for (int c = 0; c < 6; ++c) op[c] = acc[c];
    }
}

extern "C" void kernel_launch(void* const* d_in, const int* in_sizes, int n_in,
                              void* d_out, int out_size, void* d_ws, size_t ws_size,
                              hipStream_t stream) {
    (void)in_sizes; (void)n_in; (void)out_size; (void)d_ws; (void)ws_size;
    const float* pos   = (const float*)d_in[0];
    const float* vel   = (const float*)d_in[1];
    const float* initc = (const float*)d_in[2];
    const float* W1    = (const float*)d_in[3];
    const float* b1    = (const float*)d_in[4];
    const float* W2    = (const float*)d_in[5];
    const float* b2    = (const float*)d_in[6];
    const float* W3    = (const float*)d_in[7];
    const float* b3    = (const float*)d_in[8];
    float* out = (float*)d_out;

    knn_mlp<<<256, NTHR, 0, stream>>>(pos, vel, initc, W1, b1, W2, b2, W3, b3, out);
}

// Round 18
// 181.377 us; speedup vs baseline: 1.0373x; 1.0004x over previous
//
#include <hip/hip_runtime.h>

// B=2, N=8192, K=10, I=3, LEN_IN=66. All buffers f32.
// LOCKED correctness recipe (R8-R17, passed, absmax 0.0625):
//   sq  = fmaf(z,z, fmaf(y,y, rn(x*x)))          (asc FMA)
//   dot = fmaf(z,z', fmaf(y,y', rn(x*x')))       (asc FMA)
//   d2  = fmaf(-2,dot, rn(sq_q + sq_c))          (== single-rounded sub form)
//   selection: strict <, stable lowest-index-first (lexicographic (d2,idx))
// R18: R13 base (R17 prefetch reverted — compiler sank it, 123us) + ONE
// change: BRANCHLESS push. Store entry unconditionally at slot cnt, advance
// cnt only on (dd < thr): deletes exec-mask save/restore + branch per
// candidate (~12 ops/iter, branch ~50% unpredictable) for +1 ds_write/cand
// (4-way aliased, cheap). Dead stores overwritten; flush reads k < cnt only.
// Overflow-safe: writes at index <= 9 (cnt<=6 at check + 4 pushes), DEPTH=10.
#define NPTS   8192
#define KNN    11
#define QPB    64          // queries per block (one per lane)
#define NTHR   1024
#define NSLICE 16          // candidate slices (one per wave)
#define SLEN   (NPTS / NSLICE)   // 512
#define DEPTH  10          // per-lane push-buffer entries
#define TRIG   7           // flush when any lane cnt >= TRIG (4 pushes headroom)

__global__ __launch_bounds__(NTHR, 4) void knn_mlp(
    const float* __restrict__ pos,
    const float* __restrict__ vel,
    const float* __restrict__ initc,
    const float* __restrict__ W1,
    const float* __restrict__ b1,
    const float* __restrict__ W2,
    const float* __restrict__ b2,
    const float* __restrict__ W3,
    const float* __restrict__ b3,
    float* __restrict__ out) {

    // Phased LDS (112KB):
    //   phase-scan : [0,32K) ssq | [32K,112K) push region [k][tid] u64
    //   phase-fold : [32K, ...) fold scratch (4.3KB)
    //   phase-merge: [0,45K) pd f32 | [45K,90K) pi i32   (ssq/region dead)
    __shared__ __align__(16) char smem[32 * 1024 + NTHR * DEPTH * 8];
    __shared__ float sW[405];           // Weff[396] + bias[6] + init[3]

    float* ssq = (float*)smem;
    unsigned long long* region = (unsigned long long*)(smem + 32 * 1024);

    const int tid  = threadIdx.x;
    const int lane = tid & 63;
    const int wave = tid >> 6;
    const int b    = blockIdx.x >> 7;           // 128 blocks per batch
    const int n0   = (blockIdx.x & 127) * QPB;
    const int q    = n0 + lane;

    const float* posb = pos + b * NPTS * 3;
    const float* velb = vel + b * NPTS * 3;

    // ---- phase 1a: per-point sq into LDS (LOCKED recipe)
    for (int a = tid; a < NPTS; a += NTHR) {
        float x = posb[a * 3 + 0];
        float y = posb[a * 3 + 1];
        float z = posb[a * 3 + 2];
        ssq[a] = __fmaf_rn(z, z, __fmaf_rn(y, y, __fmul_rn(x, x)));
    }
    // ---- phase 1b: fold stage 1 (scratch in region): W12 = W1@W2, b12 = b1@W2+b2
    float* sW12 = (float*)region;
    for (int e = tid; e < 66 * 16; e += NTHR) {
        int r = e >> 4, c = e & 15;
        float s = 0.f;
        for (int j = 0; j < 32; ++j) s += W1[r * 32 + j] * W2[j * 16 + c];
        sW12[e] = s;
    }
    if (tid < 16) {
        float s = b2[tid];
        for (int j = 0; j < 32; ++j) s += b1[j] * W2[j * 16 + tid];
        sW12[66 * 16 + tid] = s;
    }
    if (tid < 3) sW[402 + tid] = initc[b * 3 + tid];
    __syncthreads();
    // ---- fold stage 2: Weff = W12@W3, bias = b12@W3 + b3
    for (int e = tid; e < 66 * 6; e += NTHR) {
        int r = e / 6, c = e - r * 6;
        float s = 0.f;
        for (int j = 0; j < 16; ++j) s += sW12[r * 16 + j] * W3[j * 6 + c];
        sW[e] = s;
    }
    if (tid < 6) {
        float s = b3[tid];
        for (int j = 0; j < 16; ++j) s += sW12[66 * 16 + j] * W3[j * 6 + tid];
        sW[396 + tid] = s;
    }
    __syncthreads();   // fold scratch done -> region becomes push buffers

    const float qx = posb[q * 3 + 0];
    const float qy = posb[q * 3 + 1];
    const float qz = posb[q * 3 + 2];
    const float sqq = ssq[q];           // identical bits to locked recipe

    // Top-11 in named scalars (register-resident; 52 VGPR verified legit).
    float d0 = 3.0e38f, d1 = 3.0e38f, d2v = 3.0e38f, d3 = 3.0e38f, d4 = 3.0e38f,
          d5 = 3.0e38f, d6 = 3.0e38f, d7 = 3.0e38f, d8 = 3.0e38f, d9 = 3.0e38f,
          d10 = 3.0e38f;
    int   i0 = 0x7FFFFFFF, i1 = 0x7FFFFFFF, i2v = 0x7FFFFFFF, i3 = 0x7FFFFFFF,
          i4 = 0x7FFFFFFF, i5 = 0x7FFFFFFF, i6 = 0x7FFFFFFF, i7 = 0x7FFFFFFF,
          i8 = 0x7FFFFFFF, i9 = 0x7FFFFFFF, i10 = 0x7FFFFFFF;

    float thr = 3.0e38f;       // own d10 copy (stale ok: only over-buffers)
    int cnt = 0;

    auto insert = [&](float nd, int nj) {
        if (nd < d10) {
            bool c, cp;
            cp = nd < d9;  d10 = cp ? d9  : nd;             i10 = cp ? i9  : nj;             c = cp;
            cp = nd < d8;  d9  = cp ? d8  : (c ? nd : d9);  i9  = cp ? i8  : (c ? nj : i9);  c = cp;
            cp = nd < d7;  d8  = cp ? d7  : (c ? nd : d8);  i8  = cp ? i7  : (c ? nj : i8);  c = cp;
            cp = nd < d6;  d7  = cp ? d6  : (c ? nd : d7);  i7  = cp ? i6  : (c ? nj : i7);  c = cp;
            cp = nd < d5;  d6  = cp ? d5  : (c ? nd : d6);  i6  = cp ? i5  : (c ? nj : i6);  c = cp;
            cp = nd < d4;  d5  = cp ? d4  : (c ? nd : d5);  i5  = cp ? i4  : (c ? nj : i5);  c = cp;
            cp = nd < d3;  d4  = cp ? d3  : (c ? nd : d4);  i4  = cp ? i3  : (c ? nj : i4);  c = cp;
            cp = nd < d2v; d3  = cp ? d2v : (c ? nd : d3);  i3  = cp ? i2v : (c ? nj : i3);  c = cp;
            cp = nd < d1;  d2v = cp ? d1  : (c ? nd : d2v); i2v = cp ? i1  : (c ? nj : i2v); c = cp;
            cp = nd < d0;  d1  = cp ? d0  : (c ? nd : d1);  i1  = cp ? i0  : (c ? nj : i1);  c = cp;
            if (c) { d0 = nd; i0 = nj; }
        }
    };

    auto flush = [&]() {
#pragma unroll 1
        for (int k = 0; __any(k < cnt); ++k) {
            if (k < cnt) {
                unsigned long long e = region[k * NTHR + tid];  // [k][tid]: 2-way only
                float nd = __uint_as_float((unsigned)(e >> 32));
                int   nj = (int)(unsigned)(e & 0xFFFFFFFFull);
                insert(nd, nj);
            }
        }
        cnt = 0;
        thr = d10;
    };

    auto proc = [&](float cx, float cy, float cz, float sqc, int j) {
        float dot = __fmaf_rn(qz, cz, __fmaf_rn(qy, cy, __fmul_rn(qx, cx)));
        float dd  = __fmaf_rn(-2.0f, dot, __fadd_rn(sqq, sqc)); // == rn(s-2dot)
        // BRANCHLESS push: unconditional store, conditional advance. Dead
        // stores are overwritten (flush reads k < cnt only).
        region[cnt * NTHR + tid] =
            (((unsigned long long)__float_as_uint(dd)) << 32) | (unsigned)j;
        cnt += (dd < thr) ? 1 : 0;
    };

    // ---- scan: flat loop, single flush site (R13 shape — the fast one).
    const int base = wave * SLEN;
    const float4* gp = (const float4*)(posb + base * 3);  // 3 float4 per 4 cands
    const float4* sp = (const float4*)(ssq + base);
#pragma unroll 1
    for (int m = 0; m < SLEN; m += 4) {
        int f = (m >> 2) * 3;
        float4 A = gp[f], Bv = gp[f + 1], C = gp[f + 2];
        float4 S = sp[m >> 2];
        int j = base + m;
        proc(A.x,  A.y,  A.z,  S.x, j + 0);
        proc(A.w,  Bv.x, Bv.y, S.y, j + 1);
        proc(Bv.z, Bv.w, C.x,  S.z, j + 2);
        proc(C.y,  C.z,  C.w,  S.w, j + 3);
        if (__any(cnt >= TRIG)) flush();                  // rare wave-uniform path
    }
    flush();

    __syncthreads();   // scans done -> smem becomes merge lists
    float* pd = (float*)smem;                       // [NTHR][11] f32
    int*   pi = (int*)(smem + NTHR * KNN * 4);      // [NTHR][11] i32
    {
        float* pw = pd + tid * KNN;
        int*   iw = pi + tid * KNN;
        pw[0] = d0;  pw[1] = d1;  pw[2] = d2v; pw[3] = d3;  pw[4] = d4;
        pw[5] = d5;  pw[6] = d6;  pw[7] = d7;  pw[8] = d8;  pw[9] = d9;
        pw[10] = d10;
        iw[0] = i0;  iw[1] = i1;  iw[2] = i2v; iw[3] = i3;  iw[4] = i4;
        iw[5] = i5;  iw[6] = i6;  iw[7] = i7;  iw[8] = i8;  iw[9] = i9;
        iw[10] = i10;
    }
    __syncthreads();

    if (tid < QPB) {
        // 16-way merge, lexicographic (d2, idx) == global stable top-11.
        int p[NSLICE]; float hd[NSLICE]; int hi[NSLICE];
#pragma unroll
        for (int s = 0; s < NSLICE; ++s) {
            p[s]  = 0;
            hd[s] = pd[(s * 64 + tid) * KNN];
            hi[s] = pi[(s * 64 + tid) * KNN];
        }
        float acc[6];
#pragma unroll
        for (int c = 0; c < 6; ++c) acc[c] = sW[396 + c];

        for (int r = 0; r < KNN; ++r) {
            float bd = 3.9e38f; int bi = 0x7FFFFFFF; int bs = 0;
#pragma unroll
            for (int s = 0; s < NSLICE; ++s) {
                bool better = (hd[s] < bd) || (hd[s] == bd && hi[s] < bi);
                bs = better ? s : bs;
                bi = better ? hi[s] : bi;
                bd = better ? hd[s] : bd;
            }
            {   // advance winning slice head
                int pp = ++p[bs];
                if (pp < KNN) {
                    hd[bs] = pd[(bs * 64 + tid) * KNN + pp];
                    hi[bs] = pi[(bs * 64 + tid) * KNN + pp];
                } else { hd[bs] = 3.9e38f; hi[bs] = 0x7FFFFFFF; }
            }

            int bg = ((unsigned)bi < (unsigned)NPTS) ? bi : 0;   // defensive

            // velocity features: slots [r*3 .. r*3+2]
            const float* vp = velb + bg * 3;
            float vx = vp[0], vy = vp[1], vz = vp[2];
            const float* w = &sW[r * 18];
#pragma unroll
            for (int c = 0; c < 6; ++c) {
                acc[c] += vx * w[c];
                acc[c] += vy * w[6 + c];
                acc[c] += vz * w[12 + c];
            }
            // offset features (positions from global, L2-hot): rank 0 = self
            if (r >= 1) {
                float ox = posb[bg * 3 + 0] - qx;
                float oy = posb[bg * 3 + 1] - qy;
                float oz = posb[bg * 3 + 2] - qz;
                const float* w2 = &sW[(33 + (r - 1) * 3) * 6];
#pragma unroll
                for (int c = 0; c < 6; ++c) {
                    acc[c] += ox * w2[c];
                    acc[c] += oy * w2[6 + c];
                    acc[c] += oz * w2[12 + c];
                }
            }
        }
        // init_config features: slots [63..65]
#pragma unroll
        for (int k3 = 0; k3 < 3; ++k3) {
            const float* w3 = &sW[(63 + k3) * 6];
            float iv = sW[402 + k3];
#pragma unroll
            for (int c = 0; c < 6; ++c) acc[c] += iv * w3[c];
        }
        acc[0] += qx; acc[1] += qy; acc[2] += qz;

        float* op = out + (b * NPTS + q) * 6;
#pragma unroll
        for (int c = 0; c < 6; ++c) op[c] = acc[c];
    }
}

extern "C" void kernel_launch(void* const* d_in, const int* in_sizes, int n_in,
                              void* d_out, int out_size, void* d_ws, size_t ws_size,
                              hipStream_t stream) {
    (void)in_sizes; (void)n_in; (void)out_size; (void)d_ws; (void)ws_size;
    const float* pos   = (const float*)d_in[0];
    const float* vel   = (const float*)d_in[1];
    const float* initc = (const float*)d_in[2];
    const float* W1    = (const float*)d_in[3];
    const float* b1    = (const float*)d_in[4];
    const float* W2    = (const float*)d_in[5];
    const float* b2    = (const float*)d_in[6];
    const float* W3    = (const float*)d_in[7];
    const float* b3    = (const float*)d_in[8];
    float* out = (float*)d_out;

    knn_mlp<<<256, NTHR, 0, stream>>>(pos, vel, initc, W1, b1, W2, b2, W3, b3, out);
}